// Round 9
// baseline (165.032 us; speedup 1.0000x reference)
//
#include <hip/hip_runtime.h>
#include <hip/hip_bf16.h>

// VQ-VAE quantize: x[32,64,64,64] NCHW fp32, codebook[512,64] fp32.
// out[0] = 1.25*SSD/8388608 ; out[1..] = codebook[argmin] in NCHW.
// R9 = R7 (best, 33.9us) + coalesced x-load mapping + unroll-4 ct loop +
// last-block loss finalize (ticket in ws, zeroed by prep each launch).
// Structure rules learned R2/R3/R5: no cross-barrier global-load register
// lifetimes; codebook B-fragments read directly from L2-resident ws.

typedef __attribute__((ext_vector_type(8))) __bf16 bf16x8;
typedef __attribute__((ext_vector_type(4))) float f32x4;

// ---- d_ws layout (bytes) ----
#define WS_CBF   0        // 65536: bf16 codebook B-fragments (32 ct x 2 kk x 1KB)
#define WS_HN2   65536    // 2048:  (1.0 - 0.5*||c||^2) f32[512]
#define WS_RED   67584    // 16384: per-wave loss partials f32[4096]
#define WS_TKT   83968    // 4:     completion ticket

// ---- main kernel LDS layout (bytes) ----
#define K_XA   0        // 8192:  bf16 x-tile [64 rows][64 d] swizzled
#define K_HN   8192     // 2048:  hn2 f32[512]
#define K_IDX  17408    // 256:   int idx[64]   (outside phase-B overlay)
#define K_DON  17664    // 4:     last-block flag
#define K_SZ   17680
// phase-B overlay: f32 qld2[64][68] = 17408 B over [0, 17408); xa/hn dead.

__device__ __forceinline__ unsigned f2b1(float f) {
  unsigned u = __float_as_uint(f);
  return (u + 0x7FFFu + ((u >> 16) & 1)) >> 16;   // RNE float->bf16 bits
}
__device__ __forceinline__ unsigned pack2(float lo, float hi) {
  return f2b1(lo) | (f2b1(hi) << 16);
}
#if defined(__has_builtin)
#  if __has_builtin(__builtin_amdgcn_perm)
#    define PACKTR(lo, hi) __builtin_amdgcn_perm(__float_as_uint(hi), \
                             __float_as_uint(lo), 0x07060302u)
#  endif
#endif
#ifndef PACKTR   // fallback: 2-op truncation pack
#  define PACKTR(lo, hi) ((__float_as_uint(hi) & 0xFFFF0000u) | \
                          (__float_as_uint(lo) >> 16))
#endif
__device__ __forceinline__ int swz(int row) {    // XOR swizzle, 16B granules
  return ((row & 7) ^ ((row >> 4) & 7)) << 4;
}

// ================= k0: codebook -> fragment layout + hn2 + ticket clear =====
__global__ void vq_prep(const float* __restrict__ cb, char* __restrict__ ws) {
  if (blockIdx.x == 0 && threadIdx.x == 0) *(unsigned*)(ws + WS_TKT) = 0u;
  const int n = blockIdx.x * 64 + threadIdx.x;    // code 0..511
  const float4* cb4 = (const float4*)cb;
  float4 f[16];
  #pragma unroll
  for (int j = 0; j < 16; ++j) f[j] = cb4[(n << 4) + j];
  float s = 0.f;
  #pragma unroll
  for (int j = 0; j < 16; ++j)
    s += f[j].x * f[j].x + f[j].y * f[j].y + f[j].z * f[j].z + f[j].w * f[j].w;
  ((float*)(ws + WS_HN2))[n] = 1.0f - 0.5f * s;   // +1 shift keeps scores >0
  const int ct = n >> 4, col = n & 15;
  // B-fragment: lane = (g<<4)|col holds code ct*16+col, k = kk*32+g*8+e
  #pragma unroll
  for (int kk = 0; kk < 2; ++kk) {
    #pragma unroll
    for (int g = 0; g < 4; ++g) {
      float4 a = f[kk * 8 + g * 2], b = f[kk * 8 + g * 2 + 1];
      uint4 u = {pack2(a.x, a.y), pack2(a.z, a.w), pack2(b.x, b.y), pack2(b.z, b.w)};
      *(uint4*)(ws + WS_CBF + (((ct << 1) + kk) << 10) + (((g << 4) | col) << 4)) = u;
    }
  }
}

// ================= k1: argmin + loss + scatter + last-block finalize ========
__global__ void __launch_bounds__(128, 4)
vq_main(const float* __restrict__ x, const float* __restrict__ cb,
        char* __restrict__ ws, float* __restrict__ out) {
  __shared__ __align__(16) char smem[K_SZ];
  char*  xaz  = smem + K_XA;
  float* hn2z = (float*)(smem + K_HN);
  int*   idxz = (int*)(smem + K_IDX);
  float* qld2 = (float*)smem;             // phase-B overlay [64 d][68 rows]
  unsigned* donz = (unsigned*)(smem + K_DON);

  const int t    = threadIdx.x;           // 0..127
  const int bid  = blockIdx.x;            // 0..2047
  const int bimg = bid >> 6;
  const int hw0  = (bid & 63) << 6;       // 64-row hw tile
  const float4*  xb4 = (const float4*)(x + (bimg << 18) + hw0);
  const float4*  cb4 = (const float4*)cb;
  const bf16x8*  cbb = (const bf16x8*)(ws + WS_CBF);   // fragment-linear
  float* red = (float*)(ws + WS_RED);

  // ---- stage X tile: coalesced reads (4 lanes = contiguous 64B) ----
  float xsq = 0.f;
  {
    const int p = t >> 2;                 // d-pair 0..31
    const int c = t & 3;                  // chunk within plane
    #pragma unroll
    for (int j = 0; j < 4; ++j) {
      const int f = c + (j << 2);         // float4 index 0..15 (rows 4f..4f+3)
      float4 A0 = xb4[((2 * p) << 10) + f];
      float4 A1 = xb4[((2 * p + 1) << 10) + f];
      const float* a0 = (const float*)&A0;
      const float* a1 = (const float*)&A1;
      #pragma unroll
      for (int u = 0; u < 4; ++u) {
        xsq = fmaf(a0[u], a0[u], xsq);
        xsq = fmaf(a1[u], a1[u], xsq);
        int r = (f << 2) + u;
        *(unsigned*)(xaz + r * 128 + ((p << 2) ^ swz(r))) = PACKTR(a0[u], a1[u]);
      }
    }
  }
  // ---- hn2 (shifted) from prep ----
  #pragma unroll
  for (int i = 0; i < 4; ++i)
    hn2z[t + (i << 7)] = ((const float*)(ws + WS_HN2))[t + (i << 7)];
  __syncthreads();

  const int lane = t & 63;
  const int wid  = t >> 6;                // 0..1
  const int lrow = lane & 15;
  const int lk2  = (lane >> 4) << 4;

  // A fragments persist in regs (2 row-subtiles x 2 k-steps)
  bf16x8 af[2][2];
  #pragma unroll
  for (int s = 0; s < 2; ++s) {
    int row = (wid << 5) + (s << 4) + lrow;
    int sw = swz(row);
    af[s][0] = *(const bf16x8*)(xaz + row * 128 + (lk2 ^ sw));
    af[s][1] = *(const bf16x8*)(xaz + row * 128 + ((lk2 ^ 64) ^ sw));
  }

  unsigned bestu[2][4];
  #pragma unroll
  for (int s = 0; s < 2; ++s)
    #pragma unroll
    for (int r = 0; r < 4; ++r) bestu[s][r] = 0u;   // keys always > 0

  const unsigned tag0 = 511u - (unsigned)lrow;

  // ---- main loop: B direct from L2, deep unroll for latency hiding ----
  #pragma unroll 4
  for (int ct = 0; ct < 32; ++ct) {
    const bf16x8 b0 = cbb[(ct << 7) + lane];        // kk=0 fragment
    const bf16x8 b1 = cbb[(ct << 7) + 64 + lane];   // kk=1 fragment
    const float hv = hn2z[(ct << 4) + lrow];        // 1 - c^2/2 (score shift)
    const unsigned tag = tag0 - (unsigned)(ct << 4);  // 511 - nc
    #pragma unroll
    for (int s = 0; s < 2; ++s) {
      f32x4 acc = {hv, hv, hv, hv};
      acc = __builtin_amdgcn_mfma_f32_16x16x32_bf16(af[s][0], b0, acc, 0, 0, 0);
      acc = __builtin_amdgcn_mfma_f32_16x16x32_bf16(af[s][1], b1, acc, 0, 0, 0);
      #pragma unroll
      for (int r = 0; r < 4; ++r) {
        unsigned key = (__float_as_uint(acc[r]) & 0xFFFFFE00u) | tag;
        bestu[s][r] = max(bestu[s][r], key);
      }
    }
  }

  // ---- cross-lane key-max over the 16 code columns + loss partial ----
  float vsum = 0.f;
  #pragma unroll
  for (int s = 0; s < 2; ++s) {
    #pragma unroll
    for (int r = 0; r < 4; ++r) {
      unsigned k = bestu[s][r];
      #pragma unroll
      for (int m = 1; m <= 8; m <<= 1) k = max(k, (unsigned)__shfl_xor(k, m, 64));
      if (lrow == 0) {
        idxz[(wid << 5) + (s << 4) + ((lane >> 4) << 2) + r] =
            (int)(511u - (k & 511u));
        vsum += __uint_as_float(k & 0xFFFFFE00u) - 1.0f;  // un-shift score
      }
    }
  }
  float lacc = xsq - 2.0f * vsum;
  #pragma unroll
  for (int m = 32; m; m >>= 1) lacc += __shfl_xor(lacc, m, 64);
  if (lane == 0) red[(bid << 1) + wid] = lacc;
  __syncthreads();                      // idx ready; xa/hn now dead

  // ---- phase B: gather code rows -> d-major LDS -> float4 NCHW store ----
  {
    const int myrow = t >> 1;           // 0..63
    const int chh   = t & 1;            // d-half
    const int myidx = idxz[myrow];
    const float4* cbr = cb4 + (myidx << 4) + (chh << 3);
    #pragma unroll
    for (int j = 0; j < 8; ++j) {
      float4 v = cbr[j];
      const int d = (chh << 5) + (j << 2);
      qld2[(d + 0) * 68 + myrow] = v.x;
      qld2[(d + 1) * 68 + myrow] = v.y;
      qld2[(d + 2) * 68 + myrow] = v.z;
      qld2[(d + 3) * 68 + myrow] = v.w;
    }
  }
  __syncthreads();
  {
    float* outq = out + 1 + (bimg << 18) + hw0;
    const int r4 = (t & 15) << 2;       // row group of 4 (float4)
    const int d0 = t >> 4;              // base d (0..7)
    #pragma unroll
    for (int i = 0; i < 8; ++i) {
      const int d = d0 + (i << 3);
      float4 v = *(const float4*)(qld2 + d * 68 + r4);    // aligned b128
      *(float4*)(outq + (d << 12) + r4) = v;              // coalesced 16B
    }
  }

  // ---- last-arriving block reduces the 4096 partials -> out[0] ----
  __threadfence();                      // make red[] stores visible device-wide
  if (t == 0) *donz = atomicAdd((unsigned*)(ws + WS_TKT), 1u);
  __syncthreads();
  if (*donz == 2047u) {
    __threadfence();                    // acquire: see all blocks' partials
    float v = 0.f;
    #pragma unroll
    for (int k = 0; k < 32; ++k) v += red[t + (k << 7)];
    #pragma unroll
    for (int m = 32; m; m >>= 1) v += __shfl_xor(v, m, 64);
    if ((t & 63) == 0) qld2[t >> 6] = v;   // 2 wave partials
    __syncthreads();
    if (t == 0) out[0] = (qld2[0] + qld2[1]) * (1.25f / 8388608.0f);
  }
}

extern "C" void kernel_launch(void* const* d_in, const int* in_sizes, int n_in,
                              void* d_out, int out_size, void* d_ws, size_t ws_size,
                              hipStream_t stream) {
  const float* x  = (const float*)d_in[0];   // 32*64*64*64 fp32 NCHW
  const float* cb = (const float*)d_in[1];   // 512*64 fp32
  float* out = (float*)d_out;                // [0]=loss, [1..]=quantized NCHW
  char*  ws  = (char*)d_ws;                  // ~84 KB used
  vq_prep<<<8, 64, 0, stream>>>(cb, ws);
  vq_main<<<2048, 128, 0, stream>>>(x, cb, ws, out);
}

// Round 10
// 38.818 us; speedup vs baseline: 4.2515x; 4.2515x over previous
//
#include <hip/hip_runtime.h>
#include <hip/hip_bf16.h>

// VQ-VAE quantize: x[32,64,64,64] NCHW fp32, codebook[512,64] fp32.
// out[0] = 1.25*SSD/8388608 ; out[1..] = codebook[argmin] in NCHW.
// R10 = R7 structure at MAX OCCUPANCY: 16 rows/wave, 4096 blocks x 128 thr
// -> 32 waves/CU (8/SIMD, HW max). LDS 9.4 KB -> 16 blocks/CU.
// launch_bounds(128,8) caps VGPR at 64 (R7's natural allocation).
// Rules kept: no cross-barrier global-load reg lifetimes (R2/R3/R5 spills),
// unroll 2 only (R9: unroll 4 -> regalloc collapse), no threadfence ticket.
// B-fragments direct from L2-resident ws; loss fused via
// SSD = sum(x^2) - 2*sum(best score), score = dot + 1 - ||c||^2/2.

typedef __attribute__((ext_vector_type(8))) __bf16 bf16x8;
typedef __attribute__((ext_vector_type(4))) float f32x4;

// ---- d_ws layout (bytes) ----
#define WS_CBF   0        // 65536: bf16 codebook B-fragments (32 ct x 2 kk x 1KB)
#define WS_HN2   65536    // 2048:  (1.0 - 0.5*||c||^2) f32[512]
#define WS_RED   67584    // 16384: per-block loss partials f32[4096]

// ---- main kernel LDS layout (bytes) ----
#define K_XA   0        // 4096:  bf16 x-tile [32 rows][64 d] swizzled
#define K_HN   4096     // 2048:  hn2 f32[512]
#define K_IDX  9216     // 128:   int idx[32]  (after the overlay region)
#define K_RED  9344     // 8:     2 wave partials
#define K_SZ   9352
// phase-B overlay: f32 qld2[64 d][36 rows] = 9216 B over [0,9216); xa/hn dead.

__device__ __forceinline__ unsigned f2b1(float f) {
  unsigned u = __float_as_uint(f);
  return (u + 0x7FFFu + ((u >> 16) & 1)) >> 16;   // RNE float->bf16 bits
}
__device__ __forceinline__ unsigned pack2(float lo, float hi) {
  return f2b1(lo) | (f2b1(hi) << 16);
}
#if defined(__has_builtin)
#  if __has_builtin(__builtin_amdgcn_perm)
#    define PACKTR(lo, hi) __builtin_amdgcn_perm(__float_as_uint(hi), \
                             __float_as_uint(lo), 0x07060302u)
#  endif
#endif
#ifndef PACKTR   // fallback: 2-op truncation pack
#  define PACKTR(lo, hi) ((__float_as_uint(hi) & 0xFFFF0000u) | \
                          (__float_as_uint(lo) >> 16))
#endif
__device__ __forceinline__ int swz(int row) {    // XOR swizzle, 16B granules
  return ((row & 7) ^ ((row >> 4) & 7)) << 4;
}

// ================= k0: codebook -> fragment layout + hn2 =================
__global__ void vq_prep(const float* __restrict__ cb, char* __restrict__ ws) {
  const int n = blockIdx.x * 64 + threadIdx.x;    // code 0..511
  const float4* cb4 = (const float4*)cb;
  float4 f[16];
  #pragma unroll
  for (int j = 0; j < 16; ++j) f[j] = cb4[(n << 4) + j];
  float s = 0.f;
  #pragma unroll
  for (int j = 0; j < 16; ++j)
    s += f[j].x * f[j].x + f[j].y * f[j].y + f[j].z * f[j].z + f[j].w * f[j].w;
  ((float*)(ws + WS_HN2))[n] = 1.0f - 0.5f * s;   // +1 shift keeps scores >0
  const int ct = n >> 4, col = n & 15;
  // B-fragment: lane = (g<<4)|col holds code ct*16+col, k = kk*32+g*8+e
  #pragma unroll
  for (int kk = 0; kk < 2; ++kk) {
    #pragma unroll
    for (int g = 0; g < 4; ++g) {
      float4 a = f[kk * 8 + g * 2], b = f[kk * 8 + g * 2 + 1];
      uint4 u = {pack2(a.x, a.y), pack2(a.z, a.w), pack2(b.x, b.y), pack2(b.z, b.w)};
      *(uint4*)(ws + WS_CBF + (((ct << 1) + kk) << 10) + (((g << 4) | col) << 4)) = u;
    }
  }
}

// ================= k1: argmin + loss + scatter =================
__global__ void __launch_bounds__(128, 8)
vq_main(const float* __restrict__ x, const float* __restrict__ cb,
        const char* __restrict__ wsr, float* __restrict__ out,
        float* __restrict__ wsw) {
  __shared__ __align__(16) char smem[K_SZ];
  char*  xaz  = smem + K_XA;
  float* hn2z = (float*)(smem + K_HN);
  int*   idxz = (int*)(smem + K_IDX);
  float* redz = (float*)(smem + K_RED);
  float* qld2 = (float*)smem;             // phase-B overlay [64 d][36 rows]

  const int t    = threadIdx.x;           // 0..127
  const int bid  = blockIdx.x;            // 0..4095
  const int bimg = bid >> 7;              // image
  const int hw0  = (bid & 127) << 5;      // 32-row hw tile
  const float4*  xb4 = (const float4*)(x + (bimg << 18) + hw0);
  const float4*  cb4 = (const float4*)cb;
  const bf16x8*  cbb = (const bf16x8*)(wsr + WS_CBF);   // fragment-linear

  // ---- stage X tile: bf16 [row][d] swizzled (trunc pack) + sum x^2 ----
  float xsq = 0.f;
  {
    const int p = t >> 2;                 // d-pair 0..31
    const int c = t & 3;                  // chunk
    #pragma unroll
    for (int j = 0; j < 2; ++j) {
      const int f = c + (j << 2);         // float4 idx 0..7 (rows 4f..4f+3)
      float4 A0 = xb4[((2 * p) << 10) + f];
      float4 A1 = xb4[((2 * p + 1) << 10) + f];
      const float* a0 = (const float*)&A0;
      const float* a1 = (const float*)&A1;
      #pragma unroll
      for (int u = 0; u < 4; ++u) {
        xsq = fmaf(a0[u], a0[u], xsq);
        xsq = fmaf(a1[u], a1[u], xsq);
        int r = (f << 2) + u;
        *(unsigned*)(xaz + r * 128 + ((p << 2) ^ swz(r))) = PACKTR(a0[u], a1[u]);
      }
    }
  }
  // ---- hn2 (shifted) from prep ----
  #pragma unroll
  for (int i = 0; i < 4; ++i)
    hn2z[t + (i << 7)] = ((const float*)(wsr + WS_HN2))[t + (i << 7)];
  __syncthreads();

  const int lane = t & 63;
  const int wid  = t >> 6;                // 0..1
  const int lrow = lane & 15;
  const int lk2  = (lane >> 4) << 4;

  // A fragments for this wave's 16 rows (2 k-steps)
  bf16x8 af0, af1;
  {
    int row = (wid << 4) + lrow;
    int sw = swz(row);
    af0 = *(const bf16x8*)(xaz + row * 128 + (lk2 ^ sw));
    af1 = *(const bf16x8*)(xaz + row * 128 + ((lk2 ^ 64) ^ sw));
  }

  unsigned bestu[4] = {0u, 0u, 0u, 0u};   // keys always > 0
  const unsigned tag0 = 511u - (unsigned)lrow;

  // ---- main loop: B direct from L2, unroll 2 (proven) ----
  #pragma unroll 2
  for (int ct = 0; ct < 32; ++ct) {
    const bf16x8 b0 = cbb[(ct << 7) + lane];        // kk=0 fragment
    const bf16x8 b1 = cbb[(ct << 7) + 64 + lane];   // kk=1 fragment
    const float hv = hn2z[(ct << 4) + lrow];        // 1 - c^2/2 (score shift)
    const unsigned tag = tag0 - (unsigned)(ct << 4);  // 511 - nc
    f32x4 acc = {hv, hv, hv, hv};
    acc = __builtin_amdgcn_mfma_f32_16x16x32_bf16(af0, b0, acc, 0, 0, 0);
    acc = __builtin_amdgcn_mfma_f32_16x16x32_bf16(af1, b1, acc, 0, 0, 0);
    #pragma unroll
    for (int r = 0; r < 4; ++r) {
      unsigned key = (__float_as_uint(acc[r]) & 0xFFFFFE00u) | tag;
      bestu[r] = max(bestu[r], key);
    }
  }

  // ---- cross-lane key-max over the 16 code columns + loss partial ----
  float vsum = 0.f;
  #pragma unroll
  for (int r = 0; r < 4; ++r) {
    unsigned k = bestu[r];
    #pragma unroll
    for (int m = 1; m <= 8; m <<= 1) k = max(k, (unsigned)__shfl_xor(k, m, 64));
    if (lrow == 0) {
      idxz[(wid << 4) + ((lane >> 4) << 2) + r] = (int)(511u - (k & 511u));
      vsum += __uint_as_float(k & 0xFFFFFE00u) - 1.0f;  // un-shift score
    }
  }
  float lacc = xsq - 2.0f * vsum;
  #pragma unroll
  for (int m = 32; m; m >>= 1) lacc += __shfl_xor(lacc, m, 64);
  if (lane == 0) redz[wid] = lacc;
  __syncthreads();                      // idx+red ready; xa/hn now dead
  if (t == 0) wsw[bid] = redz[0] + redz[1];

  // ---- phase B: gather code rows -> d-major LDS -> float4 NCHW store ----
  {
    const int myrow = t >> 2;           // 0..31
    const int q     = t & 3;            // d-quarter
    const int myidx = idxz[myrow];
    const float4* cbr = cb4 + (myidx << 4) + (q << 2);
    #pragma unroll
    for (int j = 0; j < 4; ++j) {
      float4 v = cbr[j];
      const int d = (q << 4) + (j << 2);
      qld2[(d + 0) * 36 + myrow] = v.x;
      qld2[(d + 1) * 36 + myrow] = v.y;
      qld2[(d + 2) * 36 + myrow] = v.z;
      qld2[(d + 3) * 36 + myrow] = v.w;
    }
  }
  __syncthreads();
  {
    float* outq = out + 1 + (bimg << 18) + hw0;
    const int r4 = (t & 7) << 2;        // row group of 4 (float4)
    const int d0 = t >> 3;              // base d (0..15)
    #pragma unroll
    for (int i = 0; i < 4; ++i) {
      const int d = d0 + (i << 4);
      float4 v = *(const float4*)(qld2 + d * 36 + r4);    // aligned b128
      *(float4*)(outq + (d << 12) + r4) = v;              // coalesced 16B
    }
  }
}

__global__ void vq_finalize(const float* __restrict__ ws, float* __restrict__ out) {
  int t = threadIdx.x;
  __shared__ float red[4];
  float v = 0.f;
  #pragma unroll
  for (int k = 0; k < 16; ++k) v += ws[t + (k << 8)];
  #pragma unroll
  for (int m = 32; m; m >>= 1) v += __shfl_xor(v, m, 64);
  if ((t & 63) == 0) red[t >> 6] = v;
  __syncthreads();
  if (t == 0) out[0] = (red[0] + red[1] + red[2] + red[3]) * (1.25f / 8388608.0f);
}

extern "C" void kernel_launch(void* const* d_in, const int* in_sizes, int n_in,
                              void* d_out, int out_size, void* d_ws, size_t ws_size,
                              hipStream_t stream) {
  const float* x  = (const float*)d_in[0];   // 32*64*64*64 fp32 NCHW
  const float* cb = (const float*)d_in[1];   // 512*64 fp32
  float* out = (float*)d_out;                // [0]=loss, [1..]=quantized NCHW
  char*  ws  = (char*)d_ws;                  // ~84 KB used
  vq_prep<<<8, 64, 0, stream>>>(cb, ws);
  vq_main<<<4096, 128, 0, stream>>>(x, cb, ws, out, (float*)(ws + WS_RED));
  vq_finalize<<<1, 256, 0, stream>>>((float*)(ws + WS_RED), out);
}